// Round 1
// 1820.659 us; speedup vs baseline: 1.0167x; 1.0167x over previous
//
#include <hip/hip_runtime.h>
#include <math.h>

#define B 64
#define N 1024
#define D 256
#define H 256
#define G3 768            // 3*H
#define NUM_BAGS (B*N)
#define OUTW (D+H)

typedef _Float16 h2_t __attribute__((ext_vector_type(2)));
typedef unsigned int uint32;

__device__ __forceinline__ float sigmoidf_(float x) { return 1.0f / (1.0f + expf(-x)); }

__device__ __forceinline__ float dot2f(uint32 a, uint32 b, float c) {
#if __has_builtin(__builtin_amdgcn_fdot2)
    return __builtin_amdgcn_fdot2(__builtin_bit_cast(h2_t, a), __builtin_bit_cast(h2_t, b), c, false);
#else
    h2_t x = __builtin_bit_cast(h2_t, a), y = __builtin_bit_cast(h2_t, b);
    return c + (float)x[0] * (float)y[0] + (float)x[1] * (float)y[1];
#endif
}

// ---------------------------------------------------------------------------
// Kernel 1: w_ihT[d*768+j] = w_ih[j*256+d]  (for k_table_gemm)
//           wpack[m*768+j] = pack_f16(w_hh[j*256+2m], w_hh[j*256+2m+1])
//           flags[] = 0   (per-node completion flags for the dataflow GRU)
// ---------------------------------------------------------------------------
__global__ void k_prep(const float* __restrict__ w_ih, const float* __restrict__ w_hh,
                       float* __restrict__ w_ihT, uint32* __restrict__ wpack,
                       int* __restrict__ flags) {
    int idx = blockIdx.x * blockDim.x + threadIdx.x;
    if (idx < G3 * D) {
        int j = idx / D;
        int d = idx % D;
        w_ihT[d * G3 + j] = w_ih[idx];
    }
    if (idx < G3 * 128) {
        int j = idx / 128;
        int m = idx % 128;
        float w0 = w_hh[j * D + 2 * m];
        float w1 = w_hh[j * D + 2 * m + 1];
        h2_t v = { (_Float16)w0, (_Float16)w1 };
        wpack[m * G3 + j] = __builtin_bit_cast(uint32, v);
    }
    if (idx < NUM_BAGS) flags[idx] = 0;
}

// ---------------------------------------------------------------------------
// Kernel 2: TE2 = type_emb @ w_ihT (300x768), PE2 = pos_table @ w_ihT (1000x768)
// ---------------------------------------------------------------------------
__global__ void k_table_gemm(const float* __restrict__ type_emb, const float* __restrict__ pos_table,
                             const float* __restrict__ w_ihT,
                             float* __restrict__ TE2, float* __restrict__ PE2) {
    __shared__ float row[D];
    int r = blockIdx.x;
    const float* src;
    float* dst;
    if (r < 300) { src = type_emb + (size_t)r * D;          dst = TE2 + (size_t)r * G3; }
    else         { src = pos_table + (size_t)(r - 300) * D; dst = PE2 + (size_t)(r - 300) * G3; }
    int k = threadIdx.x;
    row[k] = src[k];
    __syncthreads();
    float a0 = 0.f, a1 = 0.f, a2 = 0.f;
#pragma unroll 8
    for (int d = 0; d < D; ++d) {
        float p = row[d];
        const float* w = w_ihT + d * G3;
        a0 += p * w[k];
        a1 += p * w[k + 256];
        a2 += p * w[k + 512];
    }
    dst[k] = a0; dst[k + 256] = a1; dst[k + 512] = a2;
}

// ---------------------------------------------------------------------------
// Kernel 3: output columns [0, D)
// ---------------------------------------------------------------------------
__global__ void k_embed_out(const int* __restrict__ node_types, const int* __restrict__ child_pos,
                            const int* __restrict__ node_vals, const int* __restrict__ offsets,
                            const float* __restrict__ type_emb, const float* __restrict__ pos_table,
                            const float* __restrict__ token_emb, float* __restrict__ out, int Ltot) {
    int tid = threadIdx.x;
    int bag = blockIdx.x * 4 + (tid >> 6);
    int q   = (tid & 63) * 4;
    int b = bag >> 10;
    int i = bag & 1023;
    int t = node_types[bag];
    int c = child_pos[bag];
    int start = offsets[bag];
    int end   = (bag + 1 < NUM_BAGS) ? offsets[bag + 1] : Ltot;

    float4 s = make_float4(0.f, 0.f, 0.f, 0.f);
    for (int l = start; l < end; ++l) {
        float4 v = *(const float4*)(token_emb + (size_t)node_vals[l] * D + q);
        s.x += v.x; s.y += v.y; s.z += v.z; s.w += v.w;
    }
    int cnt = end - start; if (cnt < 1) cnt = 1;
    float inv = 4.0f / (float)cnt;
    float4 a = *(const float4*)(type_emb + (size_t)t * D + q);
    float4 p = *(const float4*)(pos_table + (size_t)c * D + q);
    float4 r;
    r.x = 4.f * a.x + 0.25f * p.x + inv * s.x;
    r.y = 4.f * a.y + 0.25f * p.y + inv * s.y;
    r.z = 4.f * a.z + 0.25f * p.z + inv * s.z;
    r.w = 4.f * a.w + 0.25f * p.w + inv * s.w;
    *(float4*)(out + ((size_t)i * B + b) * OUTW + q) = r;
}

// ---------------------------------------------------------------------------
// Kernel 4: dataflow GRU over the parent-tree.
// Node g = i*64 + b; g-order is topological (parent's g < child's g).
// 256 blocks (one per CU, residency structurally guaranteed: 12 waves/block,
// __launch_bounds__(768,3)); block k owns nodes g = k, k+256, ... in order.
// Per node: spin (thread 0, agent-scope acquire) on parent's flag, f16-dot2
// matvec with register-resident w_hh, activation, store h to out, then
// release-store own flag (barrier's vmcnt(0) drains stores; agent-release
// performs the L2 writeback for cross-XCD visibility).
// Next node's parent data is prefetched during activation when its flag is
// already set (common case), hiding the load latency.
// ---------------------------------------------------------------------------
__global__ void __launch_bounds__(768, 3) k_gru_flow(
        const int* __restrict__ node_types, const int* __restrict__ child_pos,
        const int* __restrict__ last_parent,
        const float* __restrict__ TE2, const float* __restrict__ PE2,
        const uint32* __restrict__ wpack,
        const float* __restrict__ b_ih, const float* __restrict__ b_hh,
        float* __restrict__ out, int* __restrict__ flags) {
    __shared__ __align__(16) uint32 sp[2][128];   // packed f16 parent hidden (double-buffered)
    __shared__ float gbuf[G3];
    __shared__ float nbuf[H];
    __shared__ int sMeta[2];                      // [0]=next parent idx, [1]=next readiness

    const int j = threadIdx.x;
    const int b = blockIdx.x & 63;                // g & 63 is invariant under g += 256

    // Register-resident weight row: 128 packed f16x2 dwords.
    uint32 w[128];
#pragma unroll
    for (int m = 0; m < 128; ++m) w[m] = wpack[m * G3 + j];
    const float bi = b_ih[j];
    const float bh = b_hh[j];

    const int* nt = node_types  + (size_t)b * N;
    const int* cp = child_pos   + (size_t)b * N;
    const int* lp = last_parent + (size_t)b * N;

    int cur = 0;
    const int i0 = blockIdx.x >> 6;
    int p = lp[i0];
    int rdy;                 // 1: sp[cur]/pv valid for current node; 0: must wait+load
    float pv = 0.f;          // parent hidden (f32) for threads j < H
    if (i0 == 0 || p >= i0) {            // no parent (or malformed: ref reads zeros)
        if (j < 128) sp[0][j] = 0u;
        rdy = 1;
    } else {
        rdy = 0;
    }
    float te = TE2[(size_t)nt[i0] * G3 + j];
    float pe = PE2[(size_t)cp[i0] * G3 + j];
    __syncthreads();

    for (int g = blockIdx.x; g < NUM_BAGS; g += 256) {
        const int i = g >> 6;

        if (!rdy) {          // slow path: parent wasn't ready at peek time
            const int gp = p * 64 + b;
            if (j == 0) {
                while (__hip_atomic_load(&flags[gp], __ATOMIC_ACQUIRE, __HIP_MEMORY_SCOPE_AGENT) == 0)
                    __builtin_amdgcn_s_sleep(1);
            }
            __syncthreads();
            const float* hp = out + ((size_t)p * B + b) * OUTW + D;
            if (j < 128) {
                float2 hv = *(const float2*)(hp + 2 * j);
                h2_t v = { (_Float16)hv.x, (_Float16)hv.y };
                sp[cur][j] = __builtin_bit_cast(uint32, v);
            }
            if (j < H) pv = hp[j];
            __syncthreads();
        }

        // ---- dot: gh_j = w_hh[j,:] . prev ----
        const uint32* spc = sp[cur];
        float a0 = 0.f, a1 = 0.f, a2 = 0.f, a3 = 0.f;
#pragma unroll
        for (int m = 0; m < 128; m += 4) {
            a0 = dot2f(w[m],     spc[m],     a0);
            a1 = dot2f(w[m + 1], spc[m + 1], a1);
            a2 = dot2f(w[m + 2], spc[m + 2], a2);
            a3 = dot2f(w[m + 3], spc[m + 3], a3);
        }
        float gh = (a0 + a1) + (a2 + a3) + bh;
        float gi = 4.f * te + 0.25f * pe + bi;
        if (j < 512) gbuf[j] = gi + gh;                 // r,z: pre-activation sum
        else { gbuf[j] = gh; nbuf[j - 512] = gi; }      // n: keep separate (r*hn)

        // thread 0: classify the next node while everyone dots
        if (j == 0) {
            int rdy_n = -1, p_n = 0;
            int gn = g + 256;
            if (gn < NUM_BAGS) {
                int i_n = i + 4;
                p_n = lp[i_n];
                if (p_n == i)        rdy_n = 2;   // parent is the node being computed now
                else if (p_n >= i_n) rdy_n = 3;   // malformed: zeros (matches reference)
                else rdy_n = (__hip_atomic_load(&flags[p_n * 64 + b], __ATOMIC_ACQUIRE,
                                                __HIP_MEMORY_SCOPE_AGENT) != 0) ? 1 : 0;
            }
            sMeta[0] = p_n; sMeta[1] = rdy_n;
        }
        __syncthreads();     // gbuf + sMeta ready

        const int p_n   = sMeta[0];
        const int rdy_n = sMeta[1];

        // Prefetch next node's inputs first (loads overlap the activation math).
        float pvn = 0.f; uint32 pf = 0u;
        if (rdy_n == 1) {
            const float* hp = out + ((size_t)p_n * B + b) * OUTW + D;
            if (j < 128) {
                float2 hv = *(const float2*)(hp + 2 * j);
                h2_t v = { (_Float16)hv.x, (_Float16)hv.y };
                pf = __builtin_bit_cast(uint32, v);
            }
            if (j < H) pvn = hp[j];
        }
        float te_n = 0.f, pe_n = 0.f;
        if (rdy_n >= 0) {
            const int i_n = i + 4;
            te_n = TE2[(size_t)nt[i_n] * G3 + j];
            pe_n = PE2[(size_t)cp[i_n] * G3 + j];
        }

        // ---- activation + h (threads 0..255) ----
        if (j < H) {
            float r  = sigmoidf_(gbuf[j]);
            float z  = sigmoidf_(gbuf[H + j]);
            float nn = tanhf(nbuf[j] + r * gbuf[2 * H + j]);
            float h  = (1.f - z) * nn + z * pv;
            out[((size_t)i * B + b) * OUTW + D + j] = h;
            float ho = __shfl_xor(h, 1);
            if ((j & 1) == 0) {
                h2_t v = { (_Float16)h, (_Float16)ho };
                uint32 pk = __builtin_bit_cast(uint32, v);
                if (rdy_n == 2) sp[cur ^ 1][j >> 1] = pk;   // adjacent parent: feed directly
            }
            if (rdy_n == 2) pvn = h;
        }
        if (rdy_n == 1 && j < 128) sp[cur ^ 1][j] = pf;
        if (rdy_n == 3 && j < 128) sp[cur ^ 1][j] = 0u;
        __syncthreads();     // drains out-stores (vmcnt 0) + sp writes

        if (j == 0)
            __hip_atomic_store(&flags[g], 1, __ATOMIC_RELEASE, __HIP_MEMORY_SCOPE_AGENT);

        if (rdy_n > 0) cur ^= 1;
        rdy = (rdy_n > 0) ? 1 : 0;
        p = p_n; te = te_n; pe = pe_n; pv = pvn;
    }
}

// ---------------------------------------------------------------------------
extern "C" void kernel_launch(void* const* d_in, const int* in_sizes, int n_in,
                              void* d_out, int out_size, void* d_ws, size_t ws_size,
                              hipStream_t stream) {
    const int*   node_types  = (const int*)d_in[0];
    const int*   node_vals   = (const int*)d_in[1];
    const int*   offsets     = (const int*)d_in[2];
    const int*   last_parent = (const int*)d_in[3];
    const int*   child_pos   = (const int*)d_in[4];
    const float* type_emb    = (const float*)d_in[5];
    const float* pos_table   = (const float*)d_in[6];
    const float* token_emb   = (const float*)d_in[7];
    const float* w_ih        = (const float*)d_in[8];
    const float* w_hh        = (const float*)d_in[9];
    const float* b_ih        = (const float*)d_in[10];
    const float* b_hh        = (const float*)d_in[11];
    float* out = (float*)d_out;

    // Workspace: w_ihT | TE2 | PE2 | wpack | flags  (~5.4 MB)
    float*  ws    = (float*)d_ws;
    float*  w_ihT = ws;
    float*  TE2   = w_ihT + (size_t)G3 * D;
    float*  PE2   = TE2 + (size_t)300 * G3;
    uint32* wpack = (uint32*)(PE2 + (size_t)1000 * G3);
    int*    flags = (int*)(wpack + (size_t)G3 * 128);
    int Ltot = in_sizes[1];

    hipLaunchKernelGGL(k_prep, dim3((G3 * D + 255) / 256), dim3(256), 0, stream,
                       w_ih, w_hh, w_ihT, wpack, flags);
    hipLaunchKernelGGL(k_table_gemm, dim3(1300), dim3(256), 0, stream,
                       type_emb, pos_table, w_ihT, TE2, PE2);
    hipLaunchKernelGGL(k_embed_out, dim3(NUM_BAGS / 4), dim3(256), 0, stream,
                       node_types, child_pos, node_vals, offsets,
                       type_emb, pos_table, token_emb, out, Ltot);
    hipLaunchKernelGGL(k_gru_flow, dim3(256), dim3(768), 0, stream,
                       node_types, child_pos, last_parent, TE2, PE2, wpack, b_ih, b_hh,
                       out, flags);
}